// Round 5
// baseline (61.255 us; speedup 1.0000x reference)
//
#include <hip/hip_runtime.h>
#include <math.h>

#define NFR 8
#define DD 2048
#define NS 25
#define NB 64
#define NPAIR (NS*NB)          // 1600
#define NITER 32
#define TPB 512                // 8 waves per block, one block per pair
#define CHUNK 256              // floats per row per K-tile
#define NTILE (DD/CHUNK)       // 8
#define ROWF (CHUNK+4)         // padded LDS row: 260 floats (16B-aligned, 2-way banks)
#define BUFF (16*ROWF)         // 4160 floats per buffer

typedef __attribute__((ext_vector_type(8))) short short8;
typedef __attribute__((ext_vector_type(4))) float f32x4;

// Branch-free acos, ~1e-7 rel (Cephes asinf core). Valid for |x| <= 1.
__device__ __forceinline__ float acos_fast(float x) {
    const float ax = fabsf(x);
    const bool big = ax > 0.5f;
    const float z = big ? 0.5f * (1.f - ax) : x * x;
    const float s = big ? sqrtf(z) : ax;
    float p = fmaf(z, 4.2163199048e-2f, 2.4181311049e-2f);
    p = fmaf(z, p, 4.5470025998e-2f);
    p = fmaf(z, p, 7.4953002686e-2f);
    p = fmaf(z, p, 1.6666752422e-1f);
    const float asin_s = fmaf(s * z, p, s);
    const float asin_abs = big ? (1.5707963267948966f - 2.f * asin_s) : asin_s;
    return 1.5707963267948966f - copysignf(asin_abs, x);
}

// Pack hi-bf16 of (a,b) and lo-bf16 remainders via v_perm_b32.
#define SPLIT2(a, b, HI, LO) { \
    const float ha_ = __uint_as_float(__float_as_uint(a) & 0xFFFF0000u); \
    const float hb_ = __uint_as_float(__float_as_uint(b) & 0xFFFF0000u); \
    HI = __builtin_amdgcn_perm(__float_as_uint(b), __float_as_uint(a), 0x07060302u); \
    LO = __builtin_amdgcn_perm(__float_as_uint((b) - hb_), __float_as_uint((a) - ha_), 0x07060302u); \
}

// Async DMA: 64 lanes x 16B contiguous global -> contiguous LDS (wave-uniform base).
__device__ __forceinline__ void load_lds16(const float* g, float* l) {
    __builtin_amdgcn_global_load_lds(
        (const __attribute__((address_space(1))) void*)g,
        (__attribute__((address_space(3))) void*)l, 16, 0, 0);
}

// One block (8 waves) per (s,b) pair.
// Phase 1: stage 16x256 f32 tiles (rows 0-7 sup, 8-15 tgt) via global_load_lds,
//          double-buffered; 8-way split-K; bf16 hi/lo MFMA Gram from LDS.
// Phase 2: LDS-reduce 8 partials -> 16x16 Gram; lanes 0-7 solve support Frechet,
//          lanes 8-15 target Frechet; cosine sim.
__global__ __launch_bounds__(TPB) void fused_kernel(const float* __restrict__ sup,
                                                    const float* __restrict__ tgt,
                                                    float* __restrict__ out) {
    const int p   = blockIdx.x;
    const int tid = threadIdx.x;
    const int wv  = tid >> 6;      // 0..7
    const int l   = tid & 63;
    const int row = l & 15;
    const int kg  = l >> 4;

    __shared__ float lds[2 * BUFF];          // 33280 B; later overlaid by part/graw
    float* part = lds;                       // [8][16][17] = 2176 floats
    float* graw = lds + 2176;                // 256 floats

    // Rows staged by this wave: r0 = 2*wv, r1 = r0+1 (0-7 sup, 8-15 tgt).
    const int r0 = 2 * wv;
    const float* gA = (wv < 4)
        ? sup + ((size_t)p * NFR + r0) * DD + l * 4
        : tgt + ((size_t)(p & (NB-1)) * NFR + (r0 - 8)) * DD + l * 4;
    const float* gB = gA + DD;               // next row, same lane offset
    float* dA0 = lds + r0 * ROWF;            float* dA1 = dA0 + BUFF;
    float* dB0 = lds + (r0 + 1) * ROWF;      float* dB1 = dB0 + BUFF;
    const float* frag0 = lds + row * ROWF + wv * 32 + kg * 8;
    const float* frag1 = frag0 + BUFF;

    f32x4 accA = {0.f, 0.f, 0.f, 0.f};
    f32x4 accB = {0.f, 0.f, 0.f, 0.f};

    load_lds16(gA, dA0);
    load_lds16(gB, dB0);
    __syncthreads();
    #pragma unroll
    for (int t = 0; t < NTILE; ++t) {
        if (t + 1 < NTILE) {
            if (((t + 1) & 1) == 0) { load_lds16(gA + (t+1)*CHUNK, dA0); load_lds16(gB + (t+1)*CHUNK, dB0); }
            else                    { load_lds16(gA + (t+1)*CHUNK, dA1); load_lds16(gB + (t+1)*CHUNK, dB1); }
        }
        const float* fb = ((t & 1) == 0) ? frag0 : frag1;
        const float4 f0 = *(const float4*)fb;
        const float4 f1 = *(const float4*)(fb + 4);
        union { unsigned int u[4]; short8 s8; } H, L;
        SPLIT2(f0.x, f0.y, H.u[0], L.u[0]);
        SPLIT2(f0.z, f0.w, H.u[1], L.u[1]);
        SPLIT2(f1.x, f1.y, H.u[2], L.u[2]);
        SPLIT2(f1.z, f1.w, H.u[3], L.u[3]);
        accA = __builtin_amdgcn_mfma_f32_16x16x32_bf16(H.s8, H.s8, accA, 0, 0, 0);
        accB = __builtin_amdgcn_mfma_f32_16x16x32_bf16(H.s8, L.s8, accB, 0, 0, 0);
        accB = __builtin_amdgcn_mfma_f32_16x16x32_bf16(L.s8, H.s8, accB, 0, 0, 0);
        __syncthreads();
    }

    // Partials into LDS (tile buffers are dead now; barrier above protects overlay).
    #pragma unroll
    for (int r = 0; r < 4; ++r)
        part[wv * 272 + (kg * 4 + r) * 17 + row] = accA[r] + accB[r];
    __syncthreads();

    if (tid < 256) {
        const int rr = tid >> 4, cc = tid & 15;
        float s = 0.f;
        #pragma unroll
        for (int w = 0; w < 8; ++w) s += part[w * 272 + rr * 17 + cc];
        graw[rr * 16 + cc] = s;
    }
    __syncthreads();

    if (tid < 16) {
        const int j = tid & 7;
        const int base = tid & 8;              // 0 for sup half, 8 for tgt half
        const int R = base + j;
        const int cb = base;

        const float invn_own = rsqrtf(fmaxf(graw[R * 16 + R], 1e-14f));
        float Grow[8];
        #pragma unroll
        for (int k = 0; k < 8; ++k) {
            const float invk = rsqrtf(fmaxf(graw[(cb + k) * 16 + (cb + k)], 1e-14f));
            Grow[k] = graw[R * 16 + cb + k] * invn_own * invk;
        }

        // mu0 = normalize(mean X^): a_k = rsqrt(sum G)
        float rs = 0.f;
        #pragma unroll
        for (int k = 0; k < 8; ++k) rs += Grow[k];
        rs += __shfl_xor(rs, 1, 8);
        rs += __shfl_xor(rs, 2, 8);
        rs += __shfl_xor(rs, 4, 8);
        float a_own = rsqrtf(fmaxf(rs, 6.4e-13f));
        float aAll[8];
        #pragma unroll
        for (int k = 0; k < 8; ++k) aAll[k] = a_own;

        for (int it = 0; it < NITER; ++it) {
            float dot = 0.f;
            #pragma unroll
            for (int k = 0; k < 8; ++k) dot = fmaf(Grow[k], aAll[k], dot);
            dot = fminf(fmaxf(dot, -1.f + 1e-6f), 1.f - 1e-6f);
            const float theta = acos_fast(dot);
            const float q = fmaf(-dot, dot, 1.0f);          // sin^2(theta)
            const float coef = (theta > 1e-4f) ? theta * rsqrtf(q) : 1.f;
            const float w = 0.125f * coef;
            float wAll[8];
            #pragma unroll
            for (int k = 0; k < 8; ++k) wAll[k] = __shfl(w, base + k, 16);
            float Gw = 0.f;
            #pragma unroll
            for (int k = 0; k < 8; ++k) Gw = fmaf(Grow[k], wAll[k], Gw);
            // two interleaved 8-lane reductions: cdavg = a^T G w, wGw = w^T G w
            float u1 = a_own * Gw, u2 = w * Gw;
            u1 += __shfl_xor(u1, 1, 8);  u2 += __shfl_xor(u2, 1, 8);
            u1 += __shfl_xor(u1, 2, 8);  u2 += __shfl_xor(u2, 2, 8);
            u1 += __shfl_xor(u1, 4, 8);  u2 += __shfl_xor(u2, 4, 8);
            const float cdavg = u1;
            const float vnsq = fmaxf(u2 - cdavg * cdavg, 0.f);   // ||v||^2
            const float vn = sqrtf(vnsq);
            const float rev = vn * 0.15915494309189535f;
            const float sinv = __builtin_amdgcn_sinf(rev);       // sin(vn)
            const float cosv = __builtin_amdgcn_cosf(rev);       // cos(vn)
            const float sinc = (vn > 1e-9f) ? sinv / vn : 1.f;
            // ||mu_new||^2 = cos^2 + sinc^2 * ||v||^2  (a^T G b = 0 algebraically)
            const float cn2 = fmaf(sinc * sinc, vnsq, cosv * cosv);
            const float rn = rsqrtf(fmaxf(cn2, 1e-14f));
            a_own = (cosv * a_own + sinc * fmaf(-cdavg, a_own, w)) * rn;
            #pragma unroll
            for (int k = 0; k < 8; ++k)
                aAll[k] = (cosv * aAll[k] + sinc * fmaf(-cdavg, aAll[k], wAll[k])) * rn;
        }

        // sim = sum_{j,l} ahat_sup_j * Craw[j][l] * ahat_tgt_l
        const float ahat = a_own * invn_own;
        float at[8];
        #pragma unroll
        for (int q2 = 0; q2 < 8; ++q2) at[q2] = __shfl(ahat, 8 + q2, 16);
        float tacc = 0.f;
        #pragma unroll
        for (int q2 = 0; q2 < 8; ++q2) tacc = fmaf(graw[j * 16 + 8 + q2], at[q2], tacc);
        float sim = ahat * tacc;
        sim += __shfl_xor(sim, 1, 8);
        sim += __shfl_xor(sim, 2, 8);
        sim += __shfl_xor(sim, 4, 8);
        if (tid == 0) out[p] = sim;
    }
}

extern "C" void kernel_launch(void* const* d_in, const int* in_sizes, int n_in,
                              void* d_out, int out_size, void* d_ws, size_t ws_size,
                              hipStream_t stream) {
    const float* sup = (const float*)d_in[0];   // [25,64,8,2048] f32
    const float* tgt = (const float*)d_in[1];   // [64,8,2048] f32
    float* out = (float*)d_out;                 // [25,64] f32
    fused_kernel<<<NPAIR, TPB, 0, stream>>>(sup, tgt, out);
}

// Round 6
// 52.069 us; speedup vs baseline: 1.1764x; 1.1764x over previous
//
#include <hip/hip_runtime.h>
#include <math.h>

#define NFR 8
#define DD 2048
#define NS 25
#define NB 64
#define NSG 13                 // s-pair groups: sg covers s = {2sg, 2sg+1<25 ? : 24}
#define NBLK (NB*NSG)          // 832
#define TPB 256                // 4 waves; wave w owns K-slice [w*512, w*512+512)
#define NCH 16                 // chunks of K=32 per wave
#define NITER 32

typedef __attribute__((ext_vector_type(8))) short short8;
typedef __attribute__((ext_vector_type(4))) float f32x4;

// Branch-free acos, ~1e-7 rel (Cephes asinf core). Valid for |x| <= 1.
__device__ __forceinline__ float acos_fast(float x) {
    const float ax = fabsf(x);
    const bool big = ax > 0.5f;
    const float z = big ? 0.5f * (1.f - ax) : x * x;
    const float s = big ? sqrtf(z) : ax;
    float p = fmaf(z, 4.2163199048e-2f, 2.4181311049e-2f);
    p = fmaf(z, p, 4.5470025998e-2f);
    p = fmaf(z, p, 7.4953002686e-2f);
    p = fmaf(z, p, 1.6666752422e-1f);
    const float asin_s = fmaf(s * z, p, s);
    const float asin_abs = big ? (1.5707963267948966f - 2.f * asin_s) : asin_s;
    return 1.5707963267948966f - copysignf(asin_abs, x);
}

// Pack hi-bf16 of (a,b) and lo-bf16 remainders via v_perm_b32.
#define SPLIT2(a, b, HI, LO) { \
    const float ha_ = __uint_as_float(__float_as_uint(a) & 0xFFFF0000u); \
    const float hb_ = __uint_as_float(__float_as_uint(b) & 0xFFFF0000u); \
    HI = __builtin_amdgcn_perm(__float_as_uint(b), __float_as_uint(a), 0x07060302u); \
    LO = __builtin_amdgcn_perm(__float_as_uint((b) - hb_), __float_as_uint((a) - ha_), 0x07060302u); \
}

// One block per (b, s-pair). Phase 1: barrier-free register-streamed Gram:
//   A rows = [sup[s0] 8 rows; sup[s1] 8 rows], T rows = tgt[b] (replicated 8-15).
//   G1 = A.A^T (diag blocks = the two sup grams), G2 = A.T^T (both cross grams),
//   G3 = T.T^T (tgt gram). bf16 hi/lo split, lo*lo dropped (verified numerics).
// Phase 2: LDS-reduce 4 K-partials, build 2 synth 16x16 problems, solve both
//   concurrently with the verified 16-lane Frechet solve, write 2 outputs.
__global__ __launch_bounds__(TPB) void fused_kernel(const float* __restrict__ sup,
                                                    const float* __restrict__ tgt,
                                                    float* __restrict__ out) {
    const int b   = blockIdx.x / NSG;
    const int sg  = blockIdx.x % NSG;
    const int tid = threadIdx.x;
    const int wv  = tid >> 6;      // 0..3
    const int l   = tid & 63;
    const int row = l & 15;
    const int kg  = l >> 4;

    __shared__ float part[4 * 768];   // [wave][3][256] K-partials
    __shared__ float gsum[768];       // reduced G1,G2,G3
    __shared__ float synth[512];      // two 16x16 solve problems

    const int s0 = 2 * sg;
    const int s1 = (2 * sg + 1 < NS) ? 2 * sg + 1 : NS - 1;
    const int srow = (row < 8) ? s0 : s1;
    const float* aptr = sup + (((size_t)srow * NB + b) * NFR + (row & 7)) * DD + wv * 512 + kg * 8;
    const float* tptr = tgt + ((size_t)b * NFR + (row & 7)) * DD + wv * 512 + kg * 8;

    f32x4 acc11 = {0.f,0.f,0.f,0.f}, acc12 = {0.f,0.f,0.f,0.f};   // G1 hi.hi, cross-lo
    f32x4 acc21 = {0.f,0.f,0.f,0.f}, acc22 = {0.f,0.f,0.f,0.f};   // G2
    f32x4 acc31 = {0.f,0.f,0.f,0.f}, acc32 = {0.f,0.f,0.f,0.f};   // G3

    // 2-deep prefetch, fully unrolled (static slot indices)
    float4 pa0[2], pa1[2], pt0[2], pt1[2];
    pa0[0] = *(const float4*)(aptr +  0); pa1[0] = *(const float4*)(aptr +  4);
    pt0[0] = *(const float4*)(tptr +  0); pt1[0] = *(const float4*)(tptr +  4);
    pa0[1] = *(const float4*)(aptr + 32); pa1[1] = *(const float4*)(aptr + 36);
    pt0[1] = *(const float4*)(tptr + 32); pt1[1] = *(const float4*)(tptr + 36);

    #pragma unroll
    for (int c = 0; c < NCH; ++c) {
        const int sl = c & 1;
        const float4 fa0 = pa0[sl], fa1 = pa1[sl];
        const float4 ft0 = pt0[sl], ft1 = pt1[sl];
        if (c + 2 < NCH) {
            pa0[sl] = *(const float4*)(aptr + (c+2)*32);
            pa1[sl] = *(const float4*)(aptr + (c+2)*32 + 4);
            pt0[sl] = *(const float4*)(tptr + (c+2)*32);
            pt1[sl] = *(const float4*)(tptr + (c+2)*32 + 4);
        }
        union { unsigned int u[4]; short8 s8; } AH, AL, TH, TL;
        SPLIT2(fa0.x, fa0.y, AH.u[0], AL.u[0]);
        SPLIT2(fa0.z, fa0.w, AH.u[1], AL.u[1]);
        SPLIT2(fa1.x, fa1.y, AH.u[2], AL.u[2]);
        SPLIT2(fa1.z, fa1.w, AH.u[3], AL.u[3]);
        SPLIT2(ft0.x, ft0.y, TH.u[0], TL.u[0]);
        SPLIT2(ft0.z, ft0.w, TH.u[1], TL.u[1]);
        SPLIT2(ft1.x, ft1.y, TH.u[2], TL.u[2]);
        SPLIT2(ft1.z, ft1.w, TH.u[3], TL.u[3]);
        acc11 = __builtin_amdgcn_mfma_f32_16x16x32_bf16(AH.s8, AH.s8, acc11, 0, 0, 0);
        acc12 = __builtin_amdgcn_mfma_f32_16x16x32_bf16(AH.s8, AL.s8, acc12, 0, 0, 0);
        acc12 = __builtin_amdgcn_mfma_f32_16x16x32_bf16(AL.s8, AH.s8, acc12, 0, 0, 0);
        acc21 = __builtin_amdgcn_mfma_f32_16x16x32_bf16(AH.s8, TH.s8, acc21, 0, 0, 0);
        acc22 = __builtin_amdgcn_mfma_f32_16x16x32_bf16(AH.s8, TL.s8, acc22, 0, 0, 0);
        acc22 = __builtin_amdgcn_mfma_f32_16x16x32_bf16(AL.s8, TH.s8, acc22, 0, 0, 0);
        acc31 = __builtin_amdgcn_mfma_f32_16x16x32_bf16(TH.s8, TH.s8, acc31, 0, 0, 0);
        acc32 = __builtin_amdgcn_mfma_f32_16x16x32_bf16(TH.s8, TL.s8, acc32, 0, 0, 0);
        acc32 = __builtin_amdgcn_mfma_f32_16x16x32_bf16(TL.s8, TH.s8, acc32, 0, 0, 0);
    }

    // Dump per-wave partials: D[row=(l>>4)*4+r][col=l&15]
    {
        float* mp = part + wv * 768;
        #pragma unroll
        for (int r = 0; r < 4; ++r) {
            const int idx = (kg * 4 + r) * 16 + row;
            mp[      idx] = acc11[r] + acc12[r];
            mp[256 + idx] = acc21[r] + acc22[r];
            mp[512 + idx] = acc31[r] + acc32[r];
        }
    }
    __syncthreads();

    // K-reduce 4 partials
    for (int i = tid; i < 768; i += TPB) {
        float s = part[i] + part[768 + i] + part[1536 + i] + part[2304 + i];
        gsum[i] = s;
    }
    __syncthreads();

    // Build two synth problems: synth[g][i][j]:
    //  i<8,j<8  -> supgram_g = G1[8g+i][8g+j]
    //  i<8,j>=8 -> cross_g   = G2[8g+i][j-8]
    //  i>=8,j>=8-> tgtgram   = G3[i-8][j-8]
    for (int e2 = tid; e2 < 512; e2 += TPB) {
        const int g = e2 >> 8, e = e2 & 255;
        const int i = e >> 4, j = e & 15;
        float v = 0.f;
        if (i < 8)
            v = (j < 8) ? gsum[(i + 8*g) * 16 + (j + 8*g)]
                        : gsum[256 + (i + 8*g) * 16 + (j - 8)];
        else if (j >= 8)
            v = gsum[512 + (i - 8) * 16 + (j - 8)];
        synth[e2] = v;
    }
    __syncthreads();

    if (tid < 32) {
        const int g = tid >> 4;                 // which s of the pair
        const int t16 = tid & 15;
        const float* graw = synth + g * 256;
        const int j = t16 & 7;
        const int base = t16 & 8;               // 0 = sup half, 8 = tgt half
        const int R = base + j;
        const int cb = base;

        const float invn_own = rsqrtf(fmaxf(graw[R * 16 + R], 1e-14f));
        float Grow[8];
        #pragma unroll
        for (int k = 0; k < 8; ++k) {
            const float invk = rsqrtf(fmaxf(graw[(cb + k) * 16 + (cb + k)], 1e-14f));
            Grow[k] = graw[R * 16 + cb + k] * invn_own * invk;
        }

        // mu0 = normalize(mean X^): a_k = rsqrt(sum G)
        float rs = 0.f;
        #pragma unroll
        for (int k = 0; k < 8; ++k) rs += Grow[k];
        rs += __shfl_xor(rs, 1, 8);
        rs += __shfl_xor(rs, 2, 8);
        rs += __shfl_xor(rs, 4, 8);
        float a_own = rsqrtf(fmaxf(rs, 6.4e-13f));
        float aAll[8];
        #pragma unroll
        for (int k = 0; k < 8; ++k) aAll[k] = a_own;

        for (int it = 0; it < NITER; ++it) {
            float dot = 0.f;
            #pragma unroll
            for (int k = 0; k < 8; ++k) dot = fmaf(Grow[k], aAll[k], dot);
            dot = fminf(fmaxf(dot, -1.f + 1e-6f), 1.f - 1e-6f);
            const float theta = acos_fast(dot);
            const float q = fmaf(-dot, dot, 1.0f);          // sin^2(theta)
            const float coef = (theta > 1e-4f) ? theta * rsqrtf(q) : 1.f;
            const float w = 0.125f * coef;
            float wAll[8];
            #pragma unroll
            for (int k = 0; k < 8; ++k) wAll[k] = __shfl(w, base + k, 16);
            float Gw = 0.f;
            #pragma unroll
            for (int k = 0; k < 8; ++k) Gw = fmaf(Grow[k], wAll[k], Gw);
            // two interleaved 8-lane reductions: cdavg = a^T G w, wGw = w^T G w
            float u1 = a_own * Gw, u2 = w * Gw;
            u1 += __shfl_xor(u1, 1, 8);  u2 += __shfl_xor(u2, 1, 8);
            u1 += __shfl_xor(u1, 2, 8);  u2 += __shfl_xor(u2, 2, 8);
            u1 += __shfl_xor(u1, 4, 8);  u2 += __shfl_xor(u2, 4, 8);
            const float cdavg = u1;
            const float vnsq = fmaxf(u2 - cdavg * cdavg, 0.f);   // ||v||^2
            const float vn = sqrtf(vnsq);
            const float rev = vn * 0.15915494309189535f;
            const float sinv = __builtin_amdgcn_sinf(rev);       // sin(vn)
            const float cosv = __builtin_amdgcn_cosf(rev);       // cos(vn)
            const float sinc = (vn > 1e-9f) ? sinv / vn : 1.f;
            // ||mu_new||^2 = cos^2 + sinc^2 * ||v||^2  (a^T G b = 0 algebraically)
            const float cn2 = fmaf(sinc * sinc, vnsq, cosv * cosv);
            const float rn = rsqrtf(fmaxf(cn2, 1e-14f));
            a_own = (cosv * a_own + sinc * fmaf(-cdavg, a_own, w)) * rn;
            #pragma unroll
            for (int k = 0; k < 8; ++k)
                aAll[k] = (cosv * aAll[k] + sinc * fmaf(-cdavg, aAll[k], wAll[k])) * rn;
        }

        // sim = sum_{j,l} ahat_sup_j * Craw[j][l] * ahat_tgt_l
        const float ahat = a_own * invn_own;
        float at[8];
        #pragma unroll
        for (int q2 = 0; q2 < 8; ++q2) at[q2] = __shfl(ahat, 8 + q2, 16);
        float tacc = 0.f;
        #pragma unroll
        for (int q2 = 0; q2 < 8; ++q2) tacc = fmaf(graw[j * 16 + 8 + q2], at[q2], tacc);
        float sim = ahat * tacc;
        sim += __shfl_xor(sim, 1, 8);
        sim += __shfl_xor(sim, 2, 8);
        sim += __shfl_xor(sim, 4, 8);
        if (t16 == 0) {
            const int s = 2 * sg + g;
            if (s < NS) out[s * NB + b] = sim;
        }
    }
}

extern "C" void kernel_launch(void* const* d_in, const int* in_sizes, int n_in,
                              void* d_out, int out_size, void* d_ws, size_t ws_size,
                              hipStream_t stream) {
    const float* sup = (const float*)d_in[0];   // [25,64,8,2048] f32
    const float* tgt = (const float*)d_in[1];   // [64,8,2048] f32
    float* out = (float*)d_out;                 // [25,64] f32
    fused_kernel<<<NBLK, TPB, 0, stream>>>(sup, tgt, out);
}